// Round 4
// baseline (108.610 us; speedup 1.0000x reference)
//
#include <hip/hip_runtime.h>
#include <hip/hip_bf16.h>
#include <math.h>

typedef unsigned short u16;
typedef __attribute__((ext_vector_type(8))) short bf16x8;
typedef __attribute__((ext_vector_type(4))) float f32x4;

#define NB 128
#define ND 1024
#define NO 512
#define NK3 1536
#define EPSV 1e-5f
#define SCALEQK 0.04419417382415922f   // 1/sqrt(512)
#define LOG2E 1.4426950408889634f
#define NBLK 256

static __device__ __forceinline__ float fast_exp2(float v) {
#if __has_builtin(__builtin_amdgcn_exp2f)
  return __builtin_amdgcn_exp2f(v);
#else
  return exp2f(v);
#endif
}
static __device__ __forceinline__ float fast_rcp(float v) {
#if __has_builtin(__builtin_amdgcn_rcpf)
  return __builtin_amdgcn_rcpf(v);
#else
  return 1.f / v;
#endif
}
static __device__ __forceinline__ u16 bf16_rtn(float f) {
  unsigned u = __float_as_uint(f);
  return (u16)((u + 0x7FFFu + ((u >> 16) & 1u)) >> 16);
}
static __device__ __forceinline__ void bf16_split(float f, u16& h, u16& l) {
  h = bf16_rtn(f);
  l = bf16_rtn(f - __uint_as_float(((unsigned)h) << 16));
}
static __device__ __forceinline__ float asinh_fast(float x) {
  const float ax = fabsf(x);
  const float s = sqrtf(fmaf(ax, ax, 1.f));
  return copysignf(__logf(ax + s), x);
}
static __device__ __forceinline__ float tanh_fast(float x) {
  return 1.f - 2.f * fast_rcp(fast_exp2(x * (2.f * LOG2E)) + 1.f);
}
static __device__ __forceinline__ float sig_fast(float x) {
  return fast_rcp(1.f + fast_exp2(-x * LOG2E));
}
static __device__ __forceinline__ float sinh_fast(float x) {
  const float z = fast_exp2(x * LOG2E);
  return 0.5f * (z - fast_rcp(z));
}

// device-scope grid barrier: counters zeroed by hipMemsetAsync before launch
static __device__ __forceinline__ void grid_barrier(int* bar, int idx) {
  __syncthreads();
  if (threadIdx.x == 0) {
    __hip_atomic_fetch_add(&bar[idx], 1, __ATOMIC_ACQ_REL, __HIP_MEMORY_SCOPE_AGENT);
    while (__hip_atomic_load(&bar[idx], __ATOMIC_ACQUIRE, __HIP_MEMORY_SCOPE_AGENT) < NBLK)
      __builtin_amdgcn_s_sleep(2);
  }
  __syncthreads();
}

// =============== MFMA GEMM tile: 128 rows x 64 cols, NCH k-chunks of 64 ===============
// bf16 hi/lo 3-pass emulated fp32; LDS XOR-swizzled (byte ^= (row&7)<<4).
// AMODE: 0 = pre-split u16 (Ah/Al), 1 = fp32 inline split, 2 = fp32 asinh + split
// WMODE: 0 = plain fp32 weights W0, 1 = tanh(W0)*sigmoid(W1)
template <int AMODE, int WMODE, int NCH>
static __device__ __forceinline__ void gemm_tile(
    const float* __restrict__ Xf, const u16* __restrict__ Ah,
    const u16* __restrict__ Al, int lda, const float* __restrict__ W0,
    const float* __restrict__ W1, float* __restrict__ outp, int o0, int k0,
    char* smem) {
  u16* AshH = (u16*)smem;                // 16 KB
  u16* AshL = (u16*)(smem + 16384);      // 16 KB
  u16* BshH = (u16*)(smem + 32768);      // 8 KB
  u16* BshL = (u16*)(smem + 40960);      // 8 KB
  const int t = threadIdx.x;
  const int lane = t & 63;
  const int w = t >> 6;
  const f32x4 vz = {0.f, 0.f, 0.f, 0.f};
  f32x4 acc[2][4];
#pragma unroll
  for (int m = 0; m < 2; ++m)
#pragma unroll
    for (int n = 0; n < 4; ++n) acc[m][n] = vz;

#pragma unroll
  for (int c = 0; c < NCH; ++c) {
    const int kc = k0 + c * 64;
    if (c) __syncthreads();
    // ---- stage A: 128 rows x 64 k ----
    {
      const int row = t >> 1, half = t & 1;
      const int swz = (row & 7) << 4;
      if (AMODE == 0) {
        const u16* gh = Ah + (size_t)row * lda + kc + half * 32;
        const u16* gl = Al + (size_t)row * lda + kc + half * 32;
#pragma unroll
        for (int jj = 0; jj < 4; ++jj) {
          const uint4 vh = *(const uint4*)(gh + jj * 8);
          const uint4 vl = *(const uint4*)(gl + jj * 8);
          const int byte = (row * 128 + half * 64 + jj * 16) ^ swz;
          *(uint4*)((char*)AshH + byte) = vh;
          *(uint4*)((char*)AshL + byte) = vl;
        }
      } else {
        const float* gx = Xf + (size_t)row * lda + kc + half * 32;
#pragma unroll
        for (int jj = 0; jj < 4; ++jj) {
          const float4 v0 = *(const float4*)(gx + jj * 8);
          const float4 v1 = *(const float4*)(gx + jj * 8 + 4);
          float e[8] = {v0.x, v0.y, v0.z, v0.w, v1.x, v1.y, v1.z, v1.w};
          unsigned hp[4], lp[4];
#pragma unroll
          for (int i = 0; i < 4; ++i) {
            float a0 = e[2 * i], a1 = e[2 * i + 1];
            if (AMODE == 2) { a0 = asinh_fast(a0); a1 = asinh_fast(a1); }
            u16 h0, l0, h1, l1;
            bf16_split(a0, h0, l0);
            bf16_split(a1, h1, l1);
            hp[i] = (unsigned)h0 | ((unsigned)h1 << 16);
            lp[i] = (unsigned)l0 | ((unsigned)l1 << 16);
          }
          const int byte = (row * 128 + half * 64 + jj * 16) ^ swz;
          *(uint4*)((char*)AshH + byte) = make_uint4(hp[0], hp[1], hp[2], hp[3]);
          *(uint4*)((char*)AshL + byte) = make_uint4(lp[0], lp[1], lp[2], lp[3]);
        }
      }
    }
    // ---- stage B transposed: Bsh[col][k], 64 cols x 64 k ----
#pragma unroll
    for (int s2 = 0; s2 < 2; ++s2) {
      const int s = t + s2 * 256;
      const int kp = s >> 4, og = s & 15;
      const int gk = kc + kp * 2, go = o0 + og * 4;
      float4 w0 = *(const float4*)&W0[(size_t)gk * NO + go];
      float4 w1 = *(const float4*)&W0[(size_t)(gk + 1) * NO + go];
      if (WMODE) {
        const float4 m0 = *(const float4*)&W1[(size_t)gk * NO + go];
        const float4 m1 = *(const float4*)&W1[(size_t)(gk + 1) * NO + go];
        w0.x = tanh_fast(w0.x) * sig_fast(m0.x);
        w0.y = tanh_fast(w0.y) * sig_fast(m0.y);
        w0.z = tanh_fast(w0.z) * sig_fast(m0.z);
        w0.w = tanh_fast(w0.w) * sig_fast(m0.w);
        w1.x = tanh_fast(w1.x) * sig_fast(m1.x);
        w1.y = tanh_fast(w1.y) * sig_fast(m1.y);
        w1.z = tanh_fast(w1.z) * sig_fast(m1.z);
        w1.w = tanh_fast(w1.w) * sig_fast(m1.w);
      }
      const float e0[4] = {w0.x, w0.y, w0.z, w0.w};
      const float e1[4] = {w1.x, w1.y, w1.z, w1.w};
#pragma unroll
      for (int j = 0; j < 4; ++j) {
        u16 h0, l0, h1, l1;
        bf16_split(e0[j], h0, l0);
        bf16_split(e1[j], h1, l1);
        const int col = og * 4 + j;
        const int byte = (col * 128 + kp * 4) ^ ((col & 7) << 4);
        *(unsigned*)((char*)BshH + byte) = (unsigned)h0 | ((unsigned)h1 << 16);
        *(unsigned*)((char*)BshL + byte) = (unsigned)l0 | ((unsigned)l1 << 16);
      }
    }
    __syncthreads();
    // ---- compute: 2 k-steps of 32 ----
#pragma unroll
    for (int ks2 = 0; ks2 < 2; ++ks2) {
      const int kb = ((lane >> 4) * 16) + ks2 * 64;
      bf16x8 a_h[2], a_l[2], b_h[4], b_l[4];
#pragma unroll
      for (int m = 0; m < 2; ++m) {
        const int row = w * 32 + m * 16 + (lane & 15);
        const int byte = (row * 128 + kb) ^ ((row & 7) << 4);
        a_h[m] = *(const bf16x8*)((const char*)AshH + byte);
        a_l[m] = *(const bf16x8*)((const char*)AshL + byte);
      }
#pragma unroll
      for (int n = 0; n < 4; ++n) {
        const int col = n * 16 + (lane & 15);
        const int byte = (col * 128 + kb) ^ ((col & 7) << 4);
        b_h[n] = *(const bf16x8*)((const char*)BshH + byte);
        b_l[n] = *(const bf16x8*)((const char*)BshL + byte);
      }
#pragma unroll
      for (int m = 0; m < 2; ++m)
#pragma unroll
        for (int n = 0; n < 4; ++n) {
          acc[m][n] = __builtin_amdgcn_mfma_f32_16x16x32_bf16(a_h[m], b_h[n], acc[m][n], 0, 0, 0);
          acc[m][n] = __builtin_amdgcn_mfma_f32_16x16x32_bf16(a_h[m], b_l[n], acc[m][n], 0, 0, 0);
          acc[m][n] = __builtin_amdgcn_mfma_f32_16x16x32_bf16(a_l[m], b_h[n], acc[m][n], 0, 0, 0);
        }
    }
  }
  // ---- epilogue: C/D layout col=lane&15, row=(lane>>4)*4+reg ----
#pragma unroll
  for (int m = 0; m < 2; ++m)
#pragma unroll
    for (int n = 0; n < 4; ++n) {
      const int col = o0 + n * 16 + (lane & 15);
#pragma unroll
      for (int r = 0; r < 4; ++r) {
        const int row = w * 32 + m * 16 + (lane >> 4) * 4 + r;
        outp[(size_t)row * NO + col] = acc[m][n][r];
      }
    }
}

// =============== single fused kernel, 256 blocks, 3 grid barriers ===============
__global__ __launch_bounds__(256) void fused_all(
    const float* __restrict__ x, const float* __restrict__ gt,
    const float* __restrict__ wt, const float* __restrict__ mt,
    const float* __restrict__ k1w, const float* __restrict__ b1,
    const float* __restrict__ k3w, const float* __restrict__ b3,
    const float* __restrict__ embk, const float* __restrict__ embb,
    const float* __restrict__ ekd, const float* __restrict__ ng,
    const float* __restrict__ nbv, float* __restrict__ Tfull,
    float* __restrict__ pA, u16* __restrict__ featH, u16* __restrict__ featL,
    float* __restrict__ pB, float* __restrict__ out, int* __restrict__ bar) {
  __shared__ __align__(16) char smem[49152];
  const int bid = blockIdx.x;
  const int t = threadIdx.x;
  const int w = t >> 6;

  // ---------------- Phase 1a: attention prologue (blocks 0..127) ----------------
  if (bid < NB) {
    float* xsh = (float*)smem;                       // 4 KB
    float(*red)[4] = (float(*)[4])(smem + 4096);
    float* bc = (float*)(smem + 4096 + 7 * 4 * 4);
    *(float4*)&xsh[t * 4] = *(const float4*)&x[bid * ND + t * 4];
    float s1, s3;
    {
      float qk = embk[t], kk = embk[NO + t], qb = embb[t];
      s1 = qk * kk;
      s3 = kk * qb;
      qk = embk[t + 256]; kk = embk[NO + t + 256]; qb = embb[t + 256];
      s1 = fmaf(qk, kk, s1);
      s3 = fmaf(kk, qb, s3);
    }
#pragma unroll
    for (int off = 32; off; off >>= 1) {
      s1 += __shfl_xor(s1, off);
      s3 += __shfl_xor(s3, off);
    }
    if ((t & 63) == 0) { red[0][w] = s1; red[1][w] = s3; }
    __syncthreads();
    if (t < 2) bc[t] = red[t][0] + red[t][1] + red[t][2] + red[t][3];
    __syncthreads();
    const float S1 = bc[0], S3 = bc[1];
    const float aL2 = SCALEQK * LOG2E * S3;
    const float dS1 = SCALEQK * S1;
    float mm[7];
#pragma unroll
    for (int k = 0; k < 7; ++k) mm[k] = 0.f;
#pragma unroll
    for (int j = 0; j < 4; ++j) {
      const float xe = xsh[t * 4 + j];
      float p = fast_exp2(aL2 * xe);
      mm[0] += p;
#pragma unroll
      for (int k = 1; k < 7; ++k) { p *= xe; mm[k] += p; }
    }
#pragma unroll
    for (int off = 32; off; off >>= 1)
#pragma unroll
      for (int k = 0; k < 7; ++k) mm[k] += __shfl_xor(mm[k], off);
    if ((t & 63) == 0)
#pragma unroll
      for (int k = 0; k < 7; ++k) red[k][w] = mm[k];
    __syncthreads();
    if (t < 7) bc[2 + t] = red[t][0] + red[t][1] + red[t][2] + red[t][3];
    __syncthreads();
    const float invf[6] = {1.f, 1.f, 0.5f, 1.6666667e-1f, 4.1666668e-2f, 8.3333333e-3f};
    float cn[6], cd[6];
#pragma unroll
    for (int k = 0; k < 6; ++k) {
      cn[k] = bc[3 + k] * invf[k];
      cd[k] = bc[2 + k] * invf[k];
    }
    float Ta = 0.f;
#pragma unroll
    for (int j = 0; j < 4; ++j) {
      const int d = t * 4 + j;
      const float del = dS1 * xsh[d];
      float num = cn[5], den = cd[5];
#pragma unroll
      for (int k = 4; k >= 0; --k) {
        num = fmaf(num, del, cn[k]);
        den = fmaf(den, del, cd[k]);
      }
      Ta = fmaf(ekd[d], num / den, Ta);
    }
#pragma unroll
    for (int off = 32; off; off >>= 1) Ta += __shfl_xor(Ta, off);
    __syncthreads();
    if ((t & 63) == 0) red[0][w] = Ta;
    __syncthreads();
    if (t == 0) Tfull[bid] = red[0][0] + red[0][1] + red[0][2] + red[0][3];
    __syncthreads();  // smem handoff to gemm
  }

  // ---------------- Phase 1b: gemmA, 256 blocks (g x ksplit8 x otile8) ----------------
  {
    const int g = bid >> 6;
    const int rem = bid & 63;
    const int ks = rem >> 3, ot = rem & 7;
    const int o0 = ot * 64, k0 = ks * 128;
    float* outp = pA + (size_t)(g * 8 + ks) * (NB * NO);
    if (g == 0)
      gemm_tile<1, 0, 2>(x, nullptr, nullptr, ND, k1w, k1w, outp, o0, k0, smem);
    else if (g == 1)
      gemm_tile<1, 0, 2>(x, nullptr, nullptr, ND, gt, gt, outp, o0, k0, smem);
    else if (g == 2)
      gemm_tile<1, 1, 2>(x, nullptr, nullptr, ND, wt, mt, outp, o0, k0, smem);
    else
      gemm_tile<2, 1, 2>(x, nullptr, nullptr, ND, wt, mt, outp, o0, k0, smem);
  }
  grid_barrier(bar, 0);

  // ---------------- Phase 2: combineA -> feat (bf16 h/l) ----------------
  {
    float(*red)[4] = (float(*)[4])smem;
    float* bc = (float*)(smem + 6 * 4 * 4);
    const int p = bid * 256 + t;
    const int b = p >> 9, o = p & 511;
    float svk = 0, svb = 0, svk2 = 0, svkvb = 0, svb2 = 0, se = 0;
#pragma unroll
    for (int j = 0; j < 2; ++j) {
      const int oo = t + j * 256;
      const float vk = embk[2 * NO + oo], vb = embb[2 * NO + oo];
      svk += vk; svb += vb;
      svk2 = fmaf(vk, vk, svk2);
      svkvb = fmaf(vk, vb, svkvb);
      svb2 = fmaf(vb, vb, svb2);
    }
#pragma unroll
    for (int j = 0; j < 4; ++j) se += ekd[t + j * 256];
#pragma unroll
    for (int off = 32; off; off >>= 1) {
      svk += __shfl_xor(svk, off); svb += __shfl_xor(svb, off);
      svk2 += __shfl_xor(svk2, off); svkvb += __shfl_xor(svkvb, off);
      svb2 += __shfl_xor(svb2, off); se += __shfl_xor(se, off);
    }
    if ((t & 63) == 0) {
      red[0][w] = svk; red[1][w] = svb; red[2][w] = svk2;
      red[3][w] = svkvb; red[4][w] = svb2; red[5][w] = se;
    }
    __syncthreads();
    if (t < 6) bc[t] = red[t][0] + red[t][1] + red[t][2] + red[t][3];
    __syncthreads();
    const float inv_o = 1.f / (float)NO;
    const float mvk = bc[0] * inv_o, mvb = bc[1] * inv_o;
    const float Mvk2 = bc[2] * inv_o - mvk * mvk;
    const float Mvkvb = bc[3] * inv_o - mvk * mvb;
    const float Mvb2 = bc[4] * inv_o - mvb * mvb;
    const float E = bc[5];

    float d1 = 0, d2 = 0, d3 = 0, d4 = 0;
#pragma unroll
    for (int ks = 0; ks < 8; ++ks) {
      d1 += pA[((size_t)(0 * 8 + ks) * NB + b) * NO + o];
      d2 += pA[((size_t)(1 * 8 + ks) * NB + b) * NO + o];
      d3 += pA[((size_t)(2 * 8 + ks) * NB + b) * NO + o];
      d4 += pA[((size_t)(3 * 8 + ks) * NB + b) * NO + o];
    }
    const float c1v = d1 + b1[o];
    const float gg = sig_fast(d2);
    const float mmv = sinh_fast(d4);
    const float c3v = fmaf(gg, d3 - mmv, mmv);
    const float T = Tfull[b];
    const float vkc = embk[2 * NO + o] - mvk, vbc = embb[2 * NO + o] - mvb;
    const float var = T * T * Mvk2 + 2.f * T * E * Mvkvb + E * E * Mvb2;
    const float c4v = (T * vkc + E * vbc) * rsqrtf(var + EPSV) * ng[o] + nbv[o];

    u16* fH = featH + (size_t)b * NK3;
    u16* fL = featL + (size_t)b * NK3;
    u16 h, l;
    bf16_split(c1v, h, l); fH[o] = h; fL[o] = l;
    bf16_split(c3v, h, l); fH[NO + o] = h; fL[NO + o] = l;
    bf16_split(c4v, h, l); fH[2 * NO + o] = h; fL[2 * NO + o] = l;
  }
  grid_barrier(bar, 1);

  // ---------------- Phase 3: gemmB (96 blocks: ksplit12 x otile8) ----------------
  if (bid < 96) {
    const int ks = bid >> 3, ot = bid & 7;
    gemm_tile<0, 0, 2>(nullptr, featH, featL, NK3, k3w, k3w,
                       pB + (size_t)ks * (NB * NO), ot * 64, ks * 128, smem);
  }
  grid_barrier(bar, 2);

  // ---------------- Phase 4: combineB -> out ----------------
  {
    const int p = bid * 256 + t;
    const int b = p >> 9, o = p & 511;
    float s = b3[o];
#pragma unroll
    for (int ks = 0; ks < 12; ++ks) s += pB[((size_t)ks * NB + b) * NO + o];
    out[p] = s;
  }
}

extern "C" void kernel_launch(void* const* d_in, const int* in_sizes, int n_in,
                              void* d_out, int out_size, void* d_ws, size_t ws_size,
                              hipStream_t stream) {
  const float* x    = (const float*)d_in[0];
  const float* gt   = (const float*)d_in[1];
  const float* wt   = (const float*)d_in[2];
  const float* mt   = (const float*)d_in[3];
  const float* k1   = (const float*)d_in[4];
  const float* b1   = (const float*)d_in[5];
  const float* k3   = (const float*)d_in[6];
  const float* b3   = (const float*)d_in[7];
  const float* embk = (const float*)d_in[8];
  const float* embb = (const float*)d_in[9];
  const float* ekd  = (const float*)d_in[10];
  const float* ng   = (const float*)d_in[11];
  const float* nb   = (const float*)d_in[12];

  char* wsb = (char*)d_ws;
  int* bar = (int*)wsb;                                 // 3 counters @ 0
  float* Tfull = (float*)(wsb + 256);                   // 512 B
  float* pA = (float*)(wsb + (1u << 20));               // 32*128*512*4 = 8.4 MB
  u16* featH = (u16*)(wsb + (10u << 20));               // 384 KB
  u16* featL = (u16*)(wsb + (10u << 20) + (512u << 10));
  float* pB = (float*)(wsb + (11u << 20));              // 3.1 MB
  float* out = (float*)d_out;

  hipMemsetAsync(wsb, 0, 64, stream);  // zero barrier counters (graph-capturable)
  hipLaunchKernelGGL(fused_all, dim3(NBLK), dim3(256), 0, stream,
                     x, gt, wt, mt, k1, b1, k3, b3, embk, embb, ekd, ng, nb,
                     Tfull, pA, featH, featL, pB, out, bar);
}

// Round 5
// 50.960 us; speedup vs baseline: 2.1313x; 2.1313x over previous
//
#include <hip/hip_runtime.h>
#include <hip/hip_bf16.h>
#include <math.h>

typedef unsigned short u16;
typedef unsigned int u32;
typedef __attribute__((ext_vector_type(8))) short bf16x8;
typedef __attribute__((ext_vector_type(4))) float f32x4;

#define NB 128
#define ND 1024
#define NO 512
#define NK3 1536
#define EPSV 1e-5f
#define SCALEQK 0.04419417382415922f   // 1/sqrt(512)
#define LOG2E 1.4426950408889634f
#define NBLK 256

static __device__ __forceinline__ float fast_exp2(float v) {
#if __has_builtin(__builtin_amdgcn_exp2f)
  return __builtin_amdgcn_exp2f(v);
#else
  return exp2f(v);
#endif
}
static __device__ __forceinline__ float fast_rcp(float v) {
#if __has_builtin(__builtin_amdgcn_rcpf)
  return __builtin_amdgcn_rcpf(v);
#else
  return 1.f / v;
#endif
}
static __device__ __forceinline__ u16 bf16_rtn(float f) {
  unsigned u = __float_as_uint(f);
  return (u16)((u + 0x7FFFu + ((u >> 16) & 1u)) >> 16);
}
static __device__ __forceinline__ void bf16_split(float f, u16& h, u16& l) {
  h = bf16_rtn(f);
  l = bf16_rtn(f - __uint_as_float(((unsigned)h) << 16));
}
static __device__ __forceinline__ float asinh_fast(float x) {
  const float ax = fabsf(x);
  const float s = sqrtf(fmaf(ax, ax, 1.f));
  return copysignf(__logf(ax + s), x);
}
static __device__ __forceinline__ float tanh_fast(float x) {
  return 1.f - 2.f * fast_rcp(fast_exp2(x * (2.f * LOG2E)) + 1.f);
}
static __device__ __forceinline__ float sig_fast(float x) {
  return fast_rcp(1.f + fast_exp2(-x * LOG2E));
}
static __device__ __forceinline__ float sinh_fast(float x) {
  const float z = fast_exp2(x * LOG2E);
  return 0.5f * (z - fast_rcp(z));
}

// ---- coherent (IC-point, sc1) accesses: NO cache-maintenance ops ----
static __device__ __forceinline__ void cstoref(float* p, float v) {
  __hip_atomic_store(p, v, __ATOMIC_RELAXED, __HIP_MEMORY_SCOPE_AGENT);
}
static __device__ __forceinline__ float cloadf(const float* p) {
  return __hip_atomic_load(p, __ATOMIC_RELAXED, __HIP_MEMORY_SCOPE_AGENT);
}
static __device__ __forceinline__ void cstoreu(u32* p, u32 v) {
  __hip_atomic_store(p, v, __ATOMIC_RELAXED, __HIP_MEMORY_SCOPE_AGENT);
}
static __device__ __forceinline__ u32 cloadu(const u32* p) {
  return __hip_atomic_load(p, __ATOMIC_RELAXED, __HIP_MEMORY_SCOPE_AGENT);
}

// grid barrier: relaxed add + relaxed spin; producer flush = vmcnt(0) on sc1 stores.
// No buffer_inv / buffer_wbl2 anywhere (those caused R4's 100us stall).
static __device__ __forceinline__ void grid_barrier(int* bar, int idx) {
  __syncthreads();
  if (threadIdx.x == 0) {
    asm volatile("s_waitcnt vmcnt(0)" ::: "memory");
    __hip_atomic_fetch_add(&bar[idx], 1, __ATOMIC_RELAXED, __HIP_MEMORY_SCOPE_AGENT);
    while (__hip_atomic_load(&bar[idx], __ATOMIC_RELAXED, __HIP_MEMORY_SCOPE_AGENT) < NBLK)
      __builtin_amdgcn_s_sleep(8);
  }
  __syncthreads();
}

// =============== MFMA GEMM tile: 128 rows x 64 cols, NCH k-chunks of 64 ===============
// bf16 hi/lo 3-pass emulated fp32; LDS XOR-swizzled (byte ^= (row&7)<<4).
// AMODE: 0 = packed u32 feat (h<<16|l) via coherent loads, 1 = fp32 inline split, 2 = + asinh
// WMODE: 0 = plain fp32 weights W0, 1 = tanh(W0)*sigmoid(W1)
// ATOMIC: 0 = coherent store to outp (pA), 1 = atomicAdd into outp (out)
template <int AMODE, int WMODE, int ATOMIC, int NCH>
static __device__ __forceinline__ void gemm_tile(
    const float* __restrict__ Xf, const u32* __restrict__ FeatP, int lda,
    const float* __restrict__ W0, const float* __restrict__ W1,
    float* __restrict__ outp, int o0, int k0, char* smem) {
  u16* AshH = (u16*)smem;                // 16 KB
  u16* AshL = (u16*)(smem + 16384);      // 16 KB
  u16* BshH = (u16*)(smem + 32768);      // 8 KB
  u16* BshL = (u16*)(smem + 40960);      // 8 KB
  const int t = threadIdx.x;
  const int lane = t & 63;
  const int w = t >> 6;
  const f32x4 vz = {0.f, 0.f, 0.f, 0.f};
  f32x4 acc[2][4];
#pragma unroll
  for (int m = 0; m < 2; ++m)
#pragma unroll
    for (int n = 0; n < 4; ++n) acc[m][n] = vz;

#pragma unroll
  for (int c = 0; c < NCH; ++c) {
    const int kc = k0 + c * 64;
    if (c) __syncthreads();
    // ---- stage A: 128 rows x 64 k ----
    {
      const int row = t >> 1, half = t & 1;
      const int swz = (row & 7) << 4;
      if (AMODE == 0) {
        const u32* gf = FeatP + (size_t)row * lda + kc + half * 32;
#pragma unroll
        for (int jj = 0; jj < 4; ++jj) {
          u32 wv[8];
#pragma unroll
          for (int i = 0; i < 8; ++i) wv[i] = cloadu(gf + jj * 8 + i);
          u32 hp[4], lp[4];
#pragma unroll
          for (int i = 0; i < 4; ++i) {
            hp[i] = (wv[2 * i] >> 16) | (wv[2 * i + 1] & 0xFFFF0000u);
            lp[i] = (wv[2 * i] & 0xFFFFu) | (wv[2 * i + 1] << 16);
          }
          const int byte = (row * 128 + half * 64 + jj * 16) ^ swz;
          *(uint4*)((char*)AshH + byte) = make_uint4(hp[0], hp[1], hp[2], hp[3]);
          *(uint4*)((char*)AshL + byte) = make_uint4(lp[0], lp[1], lp[2], lp[3]);
        }
      } else {
        const float* gx = Xf + (size_t)row * lda + kc + half * 32;
#pragma unroll
        for (int jj = 0; jj < 4; ++jj) {
          const float4 v0 = *(const float4*)(gx + jj * 8);
          const float4 v1 = *(const float4*)(gx + jj * 8 + 4);
          float e[8] = {v0.x, v0.y, v0.z, v0.w, v1.x, v1.y, v1.z, v1.w};
          unsigned hp[4], lp[4];
#pragma unroll
          for (int i = 0; i < 4; ++i) {
            float a0 = e[2 * i], a1 = e[2 * i + 1];
            if (AMODE == 2) { a0 = asinh_fast(a0); a1 = asinh_fast(a1); }
            u16 h0, l0, h1, l1;
            bf16_split(a0, h0, l0);
            bf16_split(a1, h1, l1);
            hp[i] = (unsigned)h0 | ((unsigned)h1 << 16);
            lp[i] = (unsigned)l0 | ((unsigned)l1 << 16);
          }
          const int byte = (row * 128 + half * 64 + jj * 16) ^ swz;
          *(uint4*)((char*)AshH + byte) = make_uint4(hp[0], hp[1], hp[2], hp[3]);
          *(uint4*)((char*)AshL + byte) = make_uint4(lp[0], lp[1], lp[2], lp[3]);
        }
      }
    }
    // ---- stage B transposed: Bsh[col][k], 64 cols x 64 k ----
#pragma unroll
    for (int s2 = 0; s2 < 2; ++s2) {
      const int s = t + s2 * 256;
      const int kp = s >> 4, og = s & 15;
      const int gk = kc + kp * 2, go = o0 + og * 4;
      float4 w0 = *(const float4*)&W0[(size_t)gk * NO + go];
      float4 w1 = *(const float4*)&W0[(size_t)(gk + 1) * NO + go];
      if (WMODE) {
        const float4 m0 = *(const float4*)&W1[(size_t)gk * NO + go];
        const float4 m1 = *(const float4*)&W1[(size_t)(gk + 1) * NO + go];
        w0.x = tanh_fast(w0.x) * sig_fast(m0.x);
        w0.y = tanh_fast(w0.y) * sig_fast(m0.y);
        w0.z = tanh_fast(w0.z) * sig_fast(m0.z);
        w0.w = tanh_fast(w0.w) * sig_fast(m0.w);
        w1.x = tanh_fast(w1.x) * sig_fast(m1.x);
        w1.y = tanh_fast(w1.y) * sig_fast(m1.y);
        w1.z = tanh_fast(w1.z) * sig_fast(m1.z);
        w1.w = tanh_fast(w1.w) * sig_fast(m1.w);
      }
      const float e0[4] = {w0.x, w0.y, w0.z, w0.w};
      const float e1[4] = {w1.x, w1.y, w1.z, w1.w};
#pragma unroll
      for (int j = 0; j < 4; ++j) {
        u16 h0, l0, h1, l1;
        bf16_split(e0[j], h0, l0);
        bf16_split(e1[j], h1, l1);
        const int col = og * 4 + j;
        const int byte = (col * 128 + kp * 4) ^ ((col & 7) << 4);
        *(unsigned*)((char*)BshH + byte) = (unsigned)h0 | ((unsigned)h1 << 16);
        *(unsigned*)((char*)BshL + byte) = (unsigned)l0 | ((unsigned)l1 << 16);
      }
    }
    __syncthreads();
    // ---- compute: 2 k-steps of 32 ----
#pragma unroll
    for (int ks2 = 0; ks2 < 2; ++ks2) {
      const int kb = ((lane >> 4) * 16) + ks2 * 64;
      bf16x8 a_h[2], a_l[2], b_h[4], b_l[4];
#pragma unroll
      for (int m = 0; m < 2; ++m) {
        const int row = w * 32 + m * 16 + (lane & 15);
        const int byte = (row * 128 + kb) ^ ((row & 7) << 4);
        a_h[m] = *(const bf16x8*)((const char*)AshH + byte);
        a_l[m] = *(const bf16x8*)((const char*)AshL + byte);
      }
#pragma unroll
      for (int n = 0; n < 4; ++n) {
        const int col = n * 16 + (lane & 15);
        const int byte = (col * 128 + kb) ^ ((col & 7) << 4);
        b_h[n] = *(const bf16x8*)((const char*)BshH + byte);
        b_l[n] = *(const bf16x8*)((const char*)BshL + byte);
      }
#pragma unroll
      for (int m = 0; m < 2; ++m)
#pragma unroll
        for (int n = 0; n < 4; ++n) {
          acc[m][n] = __builtin_amdgcn_mfma_f32_16x16x32_bf16(a_h[m], b_h[n], acc[m][n], 0, 0, 0);
          acc[m][n] = __builtin_amdgcn_mfma_f32_16x16x32_bf16(a_h[m], b_l[n], acc[m][n], 0, 0, 0);
          acc[m][n] = __builtin_amdgcn_mfma_f32_16x16x32_bf16(a_l[m], b_h[n], acc[m][n], 0, 0, 0);
        }
    }
  }
  // ---- epilogue: C/D layout col=lane&15, row=(lane>>4)*4+reg ----
#pragma unroll
  for (int m = 0; m < 2; ++m)
#pragma unroll
    for (int n = 0; n < 4; ++n) {
      const int col = o0 + n * 16 + (lane & 15);
#pragma unroll
      for (int r = 0; r < 4; ++r) {
        const int row = w * 32 + m * 16 + (lane >> 4) * 4 + r;
        if (ATOMIC)
          atomicAdd(&outp[(size_t)row * NO + col], acc[m][n][r]);
        else
          cstoref(&outp[(size_t)row * NO + col], acc[m][n][r]);
      }
    }
}

// =============== single fused kernel, 256 blocks, 2 relaxed grid barriers ===============
__global__ __launch_bounds__(256) void fused_all(
    const float* __restrict__ x, const float* __restrict__ gt,
    const float* __restrict__ wt, const float* __restrict__ mt,
    const float* __restrict__ k1w, const float* __restrict__ b1,
    const float* __restrict__ k3w, const float* __restrict__ b3,
    const float* __restrict__ embk, const float* __restrict__ embb,
    const float* __restrict__ ekd, const float* __restrict__ ng,
    const float* __restrict__ nbv, float* __restrict__ Tfull,
    float* __restrict__ pA, u32* __restrict__ featP,
    float* __restrict__ out, int* __restrict__ bar) {
  __shared__ __align__(16) char smem[49152];
  const int bid = blockIdx.x;
  const int t = threadIdx.x;
  const int w = t >> 6;

  // ---------------- Phase 1a: attention prologue (blocks 0..127) ----------------
  if (bid < NB) {
    float* xsh = (float*)smem;                       // 4 KB
    float(*red)[4] = (float(*)[4])(smem + 4096);
    float* bc = (float*)(smem + 4096 + 7 * 4 * 4);
    *(float4*)&xsh[t * 4] = *(const float4*)&x[bid * ND + t * 4];
    float s1, s3;
    {
      float qk = embk[t], kk = embk[NO + t], qb = embb[t];
      s1 = qk * kk;
      s3 = kk * qb;
      qk = embk[t + 256]; kk = embk[NO + t + 256]; qb = embb[t + 256];
      s1 = fmaf(qk, kk, s1);
      s3 = fmaf(kk, qb, s3);
    }
#pragma unroll
    for (int off = 32; off; off >>= 1) {
      s1 += __shfl_xor(s1, off);
      s3 += __shfl_xor(s3, off);
    }
    if ((t & 63) == 0) { red[0][w] = s1; red[1][w] = s3; }
    __syncthreads();
    if (t < 2) bc[t] = red[t][0] + red[t][1] + red[t][2] + red[t][3];
    __syncthreads();
    const float S1 = bc[0], S3 = bc[1];
    const float aL2 = SCALEQK * LOG2E * S3;
    const float dS1 = SCALEQK * S1;
    float mm[7];
#pragma unroll
    for (int k = 0; k < 7; ++k) mm[k] = 0.f;
#pragma unroll
    for (int j = 0; j < 4; ++j) {
      const float xe = xsh[t * 4 + j];
      float p = fast_exp2(aL2 * xe);
      mm[0] += p;
#pragma unroll
      for (int k = 1; k < 7; ++k) { p *= xe; mm[k] += p; }
    }
#pragma unroll
    for (int off = 32; off; off >>= 1)
#pragma unroll
      for (int k = 0; k < 7; ++k) mm[k] += __shfl_xor(mm[k], off);
    if ((t & 63) == 0)
#pragma unroll
      for (int k = 0; k < 7; ++k) red[k][w] = mm[k];
    __syncthreads();
    if (t < 7) bc[2 + t] = red[t][0] + red[t][1] + red[t][2] + red[t][3];
    __syncthreads();
    const float invf[6] = {1.f, 1.f, 0.5f, 1.6666667e-1f, 4.1666668e-2f, 8.3333333e-3f};
    float cn[6], cd[6];
#pragma unroll
    for (int k = 0; k < 6; ++k) {
      cn[k] = bc[3 + k] * invf[k];
      cd[k] = bc[2 + k] * invf[k];
    }
    float Ta = 0.f;
#pragma unroll
    for (int j = 0; j < 4; ++j) {
      const int d = t * 4 + j;
      const float del = dS1 * xsh[d];
      float num = cn[5], den = cd[5];
#pragma unroll
      for (int k = 4; k >= 0; --k) {
        num = fmaf(num, del, cn[k]);
        den = fmaf(den, del, cd[k]);
      }
      Ta = fmaf(ekd[d], num / den, Ta);
    }
#pragma unroll
    for (int off = 32; off; off >>= 1) Ta += __shfl_xor(Ta, off);
    __syncthreads();
    if ((t & 63) == 0) red[0][w] = Ta;
    __syncthreads();
    if (t == 0) cstoref(&Tfull[bid], red[0][0] + red[0][1] + red[0][2] + red[0][3]);
    __syncthreads();  // smem handoff to gemm
  }

  // ---------------- Phase 1b: gemmA, 256 blocks (g x ksplit8 x otile8) ----------------
  {
    const int g = bid >> 6;
    const int rem = bid & 63;
    const int ks = rem >> 3, ot = rem & 7;
    const int o0 = ot * 64, k0 = ks * 128;
    float* outp = pA + (size_t)(g * 8 + ks) * (NB * NO);
    if (g == 0)
      gemm_tile<1, 0, 0, 2>(x, nullptr, ND, k1w, k1w, outp, o0, k0, smem);
    else if (g == 1)
      gemm_tile<1, 0, 0, 2>(x, nullptr, ND, gt, gt, outp, o0, k0, smem);
    else if (g == 2)
      gemm_tile<1, 1, 0, 2>(x, nullptr, ND, wt, mt, outp, o0, k0, smem);
    else
      gemm_tile<2, 1, 0, 2>(x, nullptr, ND, wt, mt, outp, o0, k0, smem);
  }
  grid_barrier(bar, 0);

  // ---------------- Phase 2: combineA -> feat (packed bf16 h|l) + out=bias ----------------
  {
    float(*red)[4] = (float(*)[4])smem;
    float* bc = (float*)(smem + 6 * 4 * 4);
    const int p = bid * 256 + t;
    const int b = p >> 9, o = p & 511;
    float svk = 0, svb = 0, svk2 = 0, svkvb = 0, svb2 = 0, se = 0;
#pragma unroll
    for (int j = 0; j < 2; ++j) {
      const int oo = t + j * 256;
      const float vk = embk[2 * NO + oo], vb = embb[2 * NO + oo];
      svk += vk; svb += vb;
      svk2 = fmaf(vk, vk, svk2);
      svkvb = fmaf(vk, vb, svkvb);
      svb2 = fmaf(vb, vb, svb2);
    }
#pragma unroll
    for (int j = 0; j < 4; ++j) se += ekd[t + j * 256];
#pragma unroll
    for (int off = 32; off; off >>= 1) {
      svk += __shfl_xor(svk, off); svb += __shfl_xor(svb, off);
      svk2 += __shfl_xor(svk2, off); svkvb += __shfl_xor(svkvb, off);
      svb2 += __shfl_xor(svb2, off); se += __shfl_xor(se, off);
    }
    if ((t & 63) == 0) {
      red[0][w] = svk; red[1][w] = svb; red[2][w] = svk2;
      red[3][w] = svkvb; red[4][w] = svb2; red[5][w] = se;
    }
    __syncthreads();
    if (t < 6) bc[t] = red[t][0] + red[t][1] + red[t][2] + red[t][3];
    __syncthreads();
    const float inv_o = 1.f / (float)NO;
    const float mvk = bc[0] * inv_o, mvb = bc[1] * inv_o;
    const float Mvk2 = bc[2] * inv_o - mvk * mvk;
    const float Mvkvb = bc[3] * inv_o - mvk * mvb;
    const float Mvb2 = bc[4] * inv_o - mvb * mvb;
    const float E = bc[5];

    float d1 = 0, d2 = 0, d3 = 0, d4 = 0;
#pragma unroll
    for (int ks = 0; ks < 8; ++ks) {
      d1 += cloadf(&pA[((size_t)(0 * 8 + ks) * NB + b) * NO + o]);
      d2 += cloadf(&pA[((size_t)(1 * 8 + ks) * NB + b) * NO + o]);
      d3 += cloadf(&pA[((size_t)(2 * 8 + ks) * NB + b) * NO + o]);
      d4 += cloadf(&pA[((size_t)(3 * 8 + ks) * NB + b) * NO + o]);
    }
    const float c1v = d1 + b1[o];
    const float gg = sig_fast(d2);
    const float mmv = sinh_fast(d4);
    const float c3v = fmaf(gg, d3 - mmv, mmv);
    const float T = cloadf(&Tfull[b]);
    const float vkc = embk[2 * NO + o] - mvk, vbc = embb[2 * NO + o] - mvb;
    const float var = T * T * Mvk2 + 2.f * T * E * Mvkvb + E * E * Mvb2;
    const float c4v = (T * vkc + E * vbc) * rsqrtf(var + EPSV) * ng[o] + nbv[o];

    u32* fP = featP + (size_t)b * NK3;
    u16 h, l;
    bf16_split(c1v, h, l); cstoreu(&fP[o], ((u32)h << 16) | l);
    bf16_split(c3v, h, l); cstoreu(&fP[NO + o], ((u32)h << 16) | l);
    bf16_split(c4v, h, l); cstoreu(&fP[2 * NO + o], ((u32)h << 16) | l);
    cstoref(&out[p], b3[o]);  // bias init for gemmB's atomic accumulation
  }
  grid_barrier(bar, 1);

  // ---------------- Phase 3: gemmB (192 blocks: ksplit24 x otile8) -> atomic out ----------------
  if (bid < 192) {
    const int ks = bid >> 3, ot = bid & 7;
    gemm_tile<0, 0, 1, 1>(nullptr, featP, NK3, k3w, k3w, out, ot * 64, ks * 64, smem);
  }
}

extern "C" void kernel_launch(void* const* d_in, const int* in_sizes, int n_in,
                              void* d_out, int out_size, void* d_ws, size_t ws_size,
                              hipStream_t stream) {
  const float* x    = (const float*)d_in[0];
  const float* gt   = (const float*)d_in[1];
  const float* wt   = (const float*)d_in[2];
  const float* mt   = (const float*)d_in[3];
  const float* k1   = (const float*)d_in[4];
  const float* b1   = (const float*)d_in[5];
  const float* k3   = (const float*)d_in[6];
  const float* b3   = (const float*)d_in[7];
  const float* embk = (const float*)d_in[8];
  const float* embb = (const float*)d_in[9];
  const float* ekd  = (const float*)d_in[10];
  const float* ng   = (const float*)d_in[11];
  const float* nb   = (const float*)d_in[12];

  char* wsb = (char*)d_ws;
  int* bar = (int*)wsb;                                 // 2 counters @ 0
  float* Tfull = (float*)(wsb + 256);                   // 512 B
  float* pA = (float*)(wsb + (1u << 20));               // 32*128*512*4 = 8.4 MB
  u32* featP = (u32*)(wsb + (10u << 20));               // 128*1536*4 = 768 KB
  float* out = (float*)d_out;

  hipMemsetAsync(wsb, 0, 64, stream);  // zero barrier counters
  hipLaunchKernelGGL(fused_all, dim3(NBLK), dim3(256), 0, stream,
                     x, gt, wt, mt, k1, b1, k3, b3, embk, embb, ekd, ng, nb,
                     Tfull, pA, featP, out, bar);
}

// Round 6
// 43.907 us; speedup vs baseline: 2.4737x; 1.1606x over previous
//
#include <hip/hip_runtime.h>
#include <hip/hip_bf16.h>
#include <math.h>

typedef unsigned short u16;
typedef unsigned int u32;
typedef __attribute__((ext_vector_type(8))) short bf16x8;
typedef __attribute__((ext_vector_type(4))) float f32x4;

#define NB 128
#define ND 1024
#define NO 512
#define NK3 1536
#define EPSV 1e-5f
#define SCALEQK 0.04419417382415922f   // 1/sqrt(512)
#define LOG2E 1.4426950408889634f
#define NBLK 256

static __device__ __forceinline__ float fast_exp2(float v) {
#if __has_builtin(__builtin_amdgcn_exp2f)
  return __builtin_amdgcn_exp2f(v);
#else
  return exp2f(v);
#endif
}
static __device__ __forceinline__ float fast_rcp(float v) {
#if __has_builtin(__builtin_amdgcn_rcpf)
  return __builtin_amdgcn_rcpf(v);
#else
  return 1.f / v;
#endif
}
static __device__ __forceinline__ u16 bf16_rtn(float f) {
  unsigned u = __float_as_uint(f);
  return (u16)((u + 0x7FFFu + ((u >> 16) & 1u)) >> 16);
}
static __device__ __forceinline__ void bf16_split(float f, u16& h, u16& l) {
  h = bf16_rtn(f);
  l = bf16_rtn(f - __uint_as_float(((unsigned)h) << 16));
}
static __device__ __forceinline__ float asinh_fast(float x) {
  const float ax = fabsf(x);
  const float s = sqrtf(fmaf(ax, ax, 1.f));
  return copysignf(__logf(ax + s), x);
}
static __device__ __forceinline__ float tanh_fast(float x) {
  return 1.f - 2.f * fast_rcp(fast_exp2(x * (2.f * LOG2E)) + 1.f);
}
static __device__ __forceinline__ float sig_fast(float x) {
  return fast_rcp(1.f + fast_exp2(-x * LOG2E));
}
static __device__ __forceinline__ float sinh_fast(float x) {
  const float z = fast_exp2(x * LOG2E);
  return 0.5f * (z - fast_rcp(z));
}

// coherent (IC-point) accesses for same-kernel cross-XCD traffic only
static __device__ __forceinline__ void cstoref(float* p, float v) {
  __hip_atomic_store(p, v, __ATOMIC_RELAXED, __HIP_MEMORY_SCOPE_AGENT);
}
static __device__ __forceinline__ float cloadf(const float* p) {
  return __hip_atomic_load(p, __ATOMIC_RELAXED, __HIP_MEMORY_SCOPE_AGENT);
}

// relaxed grid barrier (no cache-maintenance ops); counters zeroed by memset
static __device__ __forceinline__ void grid_barrier(int* bar, int idx) {
  __syncthreads();
  if (threadIdx.x == 0) {
    asm volatile("s_waitcnt vmcnt(0)" ::: "memory");
    __hip_atomic_fetch_add(&bar[idx], 1, __ATOMIC_RELAXED, __HIP_MEMORY_SCOPE_AGENT);
    while (__hip_atomic_load(&bar[idx], __ATOMIC_RELAXED, __HIP_MEMORY_SCOPE_AGENT) < NBLK)
      __builtin_amdgcn_s_sleep(8);
  }
  __syncthreads();
}

// =============== MFMA GEMM tile: 128x64, 512 threads (8 waves, 2x2 frags each) ===============
// bf16 hi/lo 3-pass emulated fp32; LDS XOR-swizzled (byte ^= (row&7)<<4).
// AMODE: 0 = packed u32 feat (h<<16|l) PLAIN vectorized loads, 1 = fp32 inline split, 2 = + asinh
// WMODE: 0 = plain fp32 weights W0, 1 = tanh(W0)*sigmoid(W1)
// ATOMIC: 0 = coherent scalar store (pA), 1 = atomicAdd (out)
template <int AMODE, int WMODE, int ATOMIC, int NCH>
static __device__ __forceinline__ void gemm_tile512(
    const float* __restrict__ Xf, const u32* __restrict__ FeatP, int lda,
    const float* __restrict__ W0, const float* __restrict__ W1,
    float* __restrict__ outp, int o0, int k0, char* smem) {
  u16* AshH = (u16*)smem;                // 16 KB
  u16* AshL = (u16*)(smem + 16384);      // 16 KB
  u16* BshH = (u16*)(smem + 32768);      // 8 KB
  u16* BshL = (u16*)(smem + 40960);      // 8 KB
  const int t = threadIdx.x;
  const int lane = t & 63;
  const int wr = (t >> 6) & 3;           // wave row-block 0..3
  const int wc = t >> 8;                 // wave col-block 0..1
  const f32x4 vz = {0.f, 0.f, 0.f, 0.f};
  f32x4 acc[2][2];
  acc[0][0] = vz; acc[0][1] = vz; acc[1][0] = vz; acc[1][1] = vz;

#pragma unroll
  for (int c = 0; c < NCH; ++c) {
    const int kc = k0 + c * 64;
    if (c) __syncthreads();
    // ---- stage A (coalesced): 16 lanes cover one row's 64 floats; 4 passes of 32 rows ----
    {
      const int rowb = t >> 4;        // 0..31
      const int c4 = (t & 15) * 4;    // word index 0..60
#pragma unroll
      for (int pass = 0; pass < 4; ++pass) {
        const int row = pass * 32 + rowb;
        const int byte = (row * 128 + c4 * 2) ^ ((row & 7) << 4);
        if (AMODE == 0) {
          const uint4 v = *(const uint4*)(FeatP + (size_t)row * lda + kc + c4);
          const u32 h0 = (v.x >> 16) | (v.y & 0xFFFF0000u);
          const u32 l0 = (v.x & 0xFFFFu) | (v.y << 16);
          const u32 h1 = (v.z >> 16) | (v.w & 0xFFFF0000u);
          const u32 l1 = (v.z & 0xFFFFu) | (v.w << 16);
          *(uint2*)((char*)AshH + byte) = make_uint2(h0, h1);
          *(uint2*)((char*)AshL + byte) = make_uint2(l0, l1);
        } else {
          const float4 v = *(const float4*)(Xf + (size_t)row * lda + kc + c4);
          float e[4] = {v.x, v.y, v.z, v.w};
          if (AMODE == 2) {
#pragma unroll
            for (int i = 0; i < 4; ++i) e[i] = asinh_fast(e[i]);
          }
          u16 h[4], l[4];
#pragma unroll
          for (int i = 0; i < 4; ++i) bf16_split(e[i], h[i], l[i]);
          *(uint2*)((char*)AshH + byte) =
              make_uint2((u32)h[0] | ((u32)h[1] << 16), (u32)h[2] | ((u32)h[3] << 16));
          *(uint2*)((char*)AshL + byte) =
              make_uint2((u32)l[0] | ((u32)l[1] << 16), (u32)l[2] | ((u32)l[3] << 16));
        }
      }
    }
    // ---- stage B transposed: Bsh[col][k-pair], 512 threads one pass ----
    {
      const int kp = t >> 4, og = t & 15;
      const int gk = kc + kp * 2, go = o0 + og * 4;
      float4 w0 = *(const float4*)&W0[(size_t)gk * NO + go];
      float4 w1 = *(const float4*)&W0[(size_t)(gk + 1) * NO + go];
      if (WMODE) {
        const float4 m0 = *(const float4*)&W1[(size_t)gk * NO + go];
        const float4 m1 = *(const float4*)&W1[(size_t)(gk + 1) * NO + go];
        w0.x = tanh_fast(w0.x) * sig_fast(m0.x);
        w0.y = tanh_fast(w0.y) * sig_fast(m0.y);
        w0.z = tanh_fast(w0.z) * sig_fast(m0.z);
        w0.w = tanh_fast(w0.w) * sig_fast(m0.w);
        w1.x = tanh_fast(w1.x) * sig_fast(m1.x);
        w1.y = tanh_fast(w1.y) * sig_fast(m1.y);
        w1.z = tanh_fast(w1.z) * sig_fast(m1.z);
        w1.w = tanh_fast(w1.w) * sig_fast(m1.w);
      }
      const float e0[4] = {w0.x, w0.y, w0.z, w0.w};
      const float e1[4] = {w1.x, w1.y, w1.z, w1.w};
#pragma unroll
      for (int j = 0; j < 4; ++j) {
        u16 h0, l0, h1, l1;
        bf16_split(e0[j], h0, l0);
        bf16_split(e1[j], h1, l1);
        const int col = og * 4 + j;
        const int byte = (col * 128 + kp * 4) ^ ((col & 7) << 4);
        *(u32*)((char*)BshH + byte) = (u32)h0 | ((u32)h1 << 16);
        *(u32*)((char*)BshL + byte) = (u32)l0 | ((u32)l1 << 16);
      }
    }
    __syncthreads();
    // ---- compute: 2 k-steps of 32 ----
#pragma unroll
    for (int ks2 = 0; ks2 < 2; ++ks2) {
      const int kb = ((lane >> 4) * 16) + ks2 * 64;
      bf16x8 a_h[2], a_l[2], b_h[2], b_l[2];
#pragma unroll
      for (int m = 0; m < 2; ++m) {
        const int row = wr * 32 + m * 16 + (lane & 15);
        const int byte = (row * 128 + kb) ^ ((row & 7) << 4);
        a_h[m] = *(const bf16x8*)((const char*)AshH + byte);
        a_l[m] = *(const bf16x8*)((const char*)AshL + byte);
      }
#pragma unroll
      for (int n = 0; n < 2; ++n) {
        const int col = wc * 32 + n * 16 + (lane & 15);
        const int byte = (col * 128 + kb) ^ ((col & 7) << 4);
        b_h[n] = *(const bf16x8*)((const char*)BshH + byte);
        b_l[n] = *(const bf16x8*)((const char*)BshL + byte);
      }
#pragma unroll
      for (int m = 0; m < 2; ++m)
#pragma unroll
        for (int n = 0; n < 2; ++n) {
          acc[m][n] = __builtin_amdgcn_mfma_f32_16x16x32_bf16(a_h[m], b_h[n], acc[m][n], 0, 0, 0);
          acc[m][n] = __builtin_amdgcn_mfma_f32_16x16x32_bf16(a_h[m], b_l[n], acc[m][n], 0, 0, 0);
          acc[m][n] = __builtin_amdgcn_mfma_f32_16x16x32_bf16(a_l[m], b_h[n], acc[m][n], 0, 0, 0);
        }
    }
  }
  // ---- epilogue: C/D layout col=lane&15, row=(lane>>4)*4+reg ----
#pragma unroll
  for (int m = 0; m < 2; ++m)
#pragma unroll
    for (int n = 0; n < 2; ++n) {
      const int col = o0 + wc * 32 + n * 16 + (lane & 15);
#pragma unroll
      for (int r = 0; r < 4; ++r) {
        const int row = wr * 32 + m * 16 + (lane >> 4) * 4 + r;
        if (ATOMIC)
          atomicAdd(&outp[(size_t)row * NO + col], acc[m][n][r]);
        else
          cstoref(&outp[(size_t)row * NO + col], acc[m][n][r]);
      }
    }
}

// =============== K1: attn + gemmA + barrier + combineA ===============
__global__ __launch_bounds__(512) void k1_fused(
    const float* __restrict__ x, const float* __restrict__ gt,
    const float* __restrict__ wt, const float* __restrict__ mt,
    const float* __restrict__ k1w, const float* __restrict__ b1,
    const float* __restrict__ b3, const float* __restrict__ embk,
    const float* __restrict__ embb, const float* __restrict__ ekd,
    const float* __restrict__ ng, const float* __restrict__ nbv,
    float* __restrict__ Tfull, float* __restrict__ pA, u32* __restrict__ featP,
    float* __restrict__ out, int* __restrict__ bar) {
  __shared__ __align__(16) char smem[49152];
  const int bid = blockIdx.x;
  const int t = threadIdx.x;
  const int w = t >> 6;

  // ---------------- Phase 1a: attention prologue (blocks 0..127) ----------------
  if (bid < NB) {
    float* xsh = (float*)smem;                        // 4 KB
    float(*red)[8] = (float(*)[8])(smem + 4096);      // 7x8
    float* bc = (float*)(smem + 4096 + 7 * 8 * 4);    // 9
    *(float2*)&xsh[t * 2] = *(const float2*)&x[bid * ND + t * 2];
    float s1, s3;
    {
      const float kk = embk[NO + t];
      s1 = embk[t] * kk;
      s3 = kk * embb[t];
    }
#pragma unroll
    for (int off = 32; off; off >>= 1) {
      s1 += __shfl_xor(s1, off);
      s3 += __shfl_xor(s3, off);
    }
    if ((t & 63) == 0) { red[0][w] = s1; red[1][w] = s3; }
    __syncthreads();
    if (t < 2) {
      float v = 0.f;
#pragma unroll
      for (int i = 0; i < 8; ++i) v += red[t][i];
      bc[t] = v;
    }
    __syncthreads();
    const float S1 = bc[0], S3 = bc[1];
    const float aL2 = SCALEQK * LOG2E * S3;
    const float dS1 = SCALEQK * S1;
    float mm[7];
#pragma unroll
    for (int k = 0; k < 7; ++k) mm[k] = 0.f;
#pragma unroll
    for (int j = 0; j < 2; ++j) {
      const float xe = xsh[t * 2 + j];
      float p = fast_exp2(aL2 * xe);
      mm[0] += p;
#pragma unroll
      for (int k = 1; k < 7; ++k) { p *= xe; mm[k] += p; }
    }
#pragma unroll
    for (int off = 32; off; off >>= 1)
#pragma unroll
      for (int k = 0; k < 7; ++k) mm[k] += __shfl_xor(mm[k], off);
    if ((t & 63) == 0)
#pragma unroll
      for (int k = 0; k < 7; ++k) red[k][w] = mm[k];
    __syncthreads();
    if (t < 7) {
      float v = 0.f;
#pragma unroll
      for (int i = 0; i < 8; ++i) v += red[t][i];
      bc[2 + t] = v;
    }
    __syncthreads();
    const float invf[6] = {1.f, 1.f, 0.5f, 1.6666667e-1f, 4.1666668e-2f, 8.3333333e-3f};
    float cn[6], cd[6];
#pragma unroll
    for (int k = 0; k < 6; ++k) {
      cn[k] = bc[3 + k] * invf[k];
      cd[k] = bc[2 + k] * invf[k];
    }
    float Ta = 0.f;
#pragma unroll
    for (int j = 0; j < 2; ++j) {
      const int d = t * 2 + j;
      const float del = dS1 * xsh[d];
      float num = cn[5], den = cd[5];
#pragma unroll
      for (int k = 4; k >= 0; --k) {
        num = fmaf(num, del, cn[k]);
        den = fmaf(den, del, cd[k]);
      }
      Ta = fmaf(ekd[d], num / den, Ta);
    }
#pragma unroll
    for (int off = 32; off; off >>= 1) Ta += __shfl_xor(Ta, off);
    __syncthreads();
    if ((t & 63) == 0) red[0][w] = Ta;
    __syncthreads();
    if (t == 0) {
      float v = 0.f;
#pragma unroll
      for (int i = 0; i < 8; ++i) v += red[0][i];
      cstoref(&Tfull[bid], v);
    }
    __syncthreads();  // smem handoff to gemm
  }

  // ---------------- Phase 1b: gemmA, 256 blocks (g x ksplit8 x otile8) ----------------
  {
    const int g = bid >> 6;
    const int rem = bid & 63;
    const int ks = rem >> 3, ot = rem & 7;
    float* outp = pA + (size_t)(g * 8 + ks) * (NB * NO);
    if (g == 0)
      gemm_tile512<1, 0, 0, 2>(x, nullptr, ND, k1w, k1w, outp, ot * 64, ks * 128, smem);
    else if (g == 1)
      gemm_tile512<1, 0, 0, 2>(x, nullptr, ND, gt, gt, outp, ot * 64, ks * 128, smem);
    else if (g == 2)
      gemm_tile512<1, 1, 0, 2>(x, nullptr, ND, wt, mt, outp, ot * 64, ks * 128, smem);
    else
      gemm_tile512<2, 1, 0, 2>(x, nullptr, ND, wt, mt, outp, ot * 64, ks * 128, smem);
  }
  grid_barrier(bar, 0);

  // ---------------- Phase 2: combineA (blocks 0..127, 1 elem/thread) ----------------
  if (bid < NB) {
    float(*red)[8] = (float(*)[8])smem;
    float* bc = (float*)(smem + 6 * 8 * 4);
    const int b = bid, o = t;
    const float vk = embk[2 * NO + o], vb = embb[2 * NO + o];
    float svk = vk, svb = vb;
    float svk2 = vk * vk, svkvb = vk * vb, svb2 = vb * vb;
    float se = ekd[o] + ekd[o + 512];
#pragma unroll
    for (int off = 32; off; off >>= 1) {
      svk += __shfl_xor(svk, off); svb += __shfl_xor(svb, off);
      svk2 += __shfl_xor(svk2, off); svkvb += __shfl_xor(svkvb, off);
      svb2 += __shfl_xor(svb2, off); se += __shfl_xor(se, off);
    }
    if ((t & 63) == 0) {
      red[0][w] = svk; red[1][w] = svb; red[2][w] = svk2;
      red[3][w] = svkvb; red[4][w] = svb2; red[5][w] = se;
    }
    __syncthreads();
    if (t < 6) {
      float v = 0.f;
#pragma unroll
      for (int i = 0; i < 8; ++i) v += red[t][i];
      bc[t] = v;
    }
    __syncthreads();
    const float inv_o = 1.f / (float)NO;
    const float mvk = bc[0] * inv_o, mvb = bc[1] * inv_o;
    const float Mvk2 = bc[2] * inv_o - mvk * mvk;
    const float Mvkvb = bc[3] * inv_o - mvk * mvb;
    const float Mvb2 = bc[4] * inv_o - mvb * mvb;
    const float E = bc[5];

    float d1 = 0, d2 = 0, d3 = 0, d4 = 0;
#pragma unroll
    for (int ks = 0; ks < 8; ++ks) {
      d1 += cloadf(&pA[((size_t)(0 * 8 + ks) * NB + b) * NO + o]);
      d2 += cloadf(&pA[((size_t)(1 * 8 + ks) * NB + b) * NO + o]);
      d3 += cloadf(&pA[((size_t)(2 * 8 + ks) * NB + b) * NO + o]);
      d4 += cloadf(&pA[((size_t)(3 * 8 + ks) * NB + b) * NO + o]);
    }
    const float c1v = d1 + b1[o];
    const float gg = sig_fast(d2);
    const float mmv = sinh_fast(d4);
    const float c3v = fmaf(gg, d3 - mmv, mmv);
    const float T = cloadf(&Tfull[b]);
    const float vkc = vk - mvk, vbc = vb - mvb;
    const float var = T * T * Mvk2 + 2.f * T * E * Mvkvb + E * E * Mvb2;
    const float c4v = (T * vkc + E * vbc) * rsqrtf(var + EPSV) * ng[o] + nbv[o];

    u32* fP = featP + (size_t)b * NK3;
    u16 h, l;
    bf16_split(c1v, h, l); fP[o] = ((u32)h << 16) | l;
    bf16_split(c3v, h, l); fP[NO + o] = ((u32)h << 16) | l;
    bf16_split(c4v, h, l); fP[2 * NO + o] = ((u32)h << 16) | l;
    out[(size_t)b * NO + o] = b3[o];  // bias init for K2 atomics (plain store; kernel
                                      // boundary provides device-scope release)
  }
}

// =============== K2: gemmB feat[128,1536] @ k3[1536,512], ksplit 8, atomic out ===============
__global__ __launch_bounds__(512) void k2_gemmB(
    const u32* __restrict__ featP, const float* __restrict__ k3w,
    float* __restrict__ out) {
  __shared__ __align__(16) char smem[49152];
  const int ks = blockIdx.x >> 3, ot = blockIdx.x & 7;
  gemm_tile512<0, 0, 1, 3>(nullptr, featP, NK3, k3w, k3w, out, ot * 64, ks * 192, smem);
}

extern "C" void kernel_launch(void* const* d_in, const int* in_sizes, int n_in,
                              void* d_out, int out_size, void* d_ws, size_t ws_size,
                              hipStream_t stream) {
  const float* x    = (const float*)d_in[0];
  const float* gt   = (const float*)d_in[1];
  const float* wt   = (const float*)d_in[2];
  const float* mt   = (const float*)d_in[3];
  const float* k1   = (const float*)d_in[4];
  const float* b1   = (const float*)d_in[5];
  const float* k3   = (const float*)d_in[6];
  const float* b3   = (const float*)d_in[7];
  const float* embk = (const float*)d_in[8];
  const float* embb = (const float*)d_in[9];
  const float* ekd  = (const float*)d_in[10];
  const float* ng   = (const float*)d_in[11];
  const float* nb   = (const float*)d_in[12];

  char* wsb = (char*)d_ws;
  int* bar = (int*)wsb;
  float* Tfull = (float*)(wsb + 256);
  float* pA = (float*)(wsb + (1u << 20));               // 32*128*512*4 = 8.4 MB
  u32* featP = (u32*)(wsb + (10u << 20));               // 128*1536*4 = 768 KB
  float* out = (float*)d_out;

  hipMemsetAsync(wsb, 0, 64, stream);  // zero barrier counters
  hipLaunchKernelGGL(k1_fused, dim3(NBLK), dim3(512), 0, stream,
                     x, gt, wt, mt, k1, b1, b3, embk, embb, ekd, ng, nb,
                     Tfull, pA, featP, out, bar);
  hipLaunchKernelGGL(k2_gemmB, dim3(64), dim3(512), 0, stream,
                     featP, k3, out);
}